// Round 3
// baseline (182.134 us; speedup 1.0000x reference)
//
#include <hip/hip_runtime.h>

#define BLANK_ID 0
#define EPS 1e-10f

constexpr int B = 8, T = 2048, D = 1024, V = 1024;

// ---------------------------------------------------------------------------
// Phase 1: per-(b,t) softmax stats. One wave64 per row of V=1024 logits.
// Each lane holds 16 elements (4x float4, coalesced). Outputs: pred=argmax,
// pval=1/sumexp (== prob of argmax), p0[b]=blank prob at t=0 (fallback only).
// ---------------------------------------------------------------------------
__global__ __launch_bounds__(256) void k_softmax_stats(
    const float* __restrict__ logits, int* __restrict__ pred,
    float* __restrict__ pval, float* __restrict__ p0) {
  const int wave = threadIdx.x >> 6;
  const int lane = threadIdx.x & 63;
  const int row  = blockIdx.x * 4 + wave;  // [0, B*T)
  const float* rp = logits + (size_t)row * V;

  float4 x[4];
#pragma unroll
  for (int j = 0; j < 4; ++j)
    x[j] = *reinterpret_cast<const float4*>(rp + j * 256 + lane * 4);

  // local max + argmax (first occurrence on ties, matching jnp.argmax)
  float m = x[0].x;
  int idx = lane * 4;
#pragma unroll
  for (int j = 0; j < 4; ++j) {
    const float v[4] = {x[j].x, x[j].y, x[j].z, x[j].w};
#pragma unroll
    for (int k = 0; k < 4; ++k) {
      const int vi = j * 256 + lane * 4 + k;
      if (v[k] > m || (v[k] == m && vi < idx)) { m = v[k]; idx = vi; }
    }
  }
#pragma unroll
  for (int off = 32; off > 0; off >>= 1) {
    const float om = __shfl_xor(m, off);
    const int   oi = __shfl_xor(idx, off);
    if (om > m || (om == m && oi < idx)) { m = om; idx = oi; }
  }

  float s = 0.f;
#pragma unroll
  for (int j = 0; j < 4; ++j)
    s += __expf(x[j].x - m) + __expf(x[j].y - m) +
         __expf(x[j].z - m) + __expf(x[j].w - m);
#pragma unroll
  for (int off = 32; off > 0; off >>= 1) s += __shfl_xor(s, off);

  if (lane == 0) {
    pred[row] = idx;
    pval[row] = 1.0f / s;
    if ((row & (T - 1)) == 0) p0[row / T] = __expf(x[0].x - m) / s;
  }
}

// ---------------------------------------------------------------------------
// Phase 2: per-batch segment scan. 1024 threads x 2 t's (was 256x8).
// Wave-level shfl_up scan (3 barriers total, was 16). seg_idx is monotone in
// t so segment s == t-range [bpos[s], bpos[s+1]). w[t]=p/(segsum+EPS) for
// contributing frames else exactly 0.
// ---------------------------------------------------------------------------
__global__ __launch_bounds__(1024) void k_segment(
    const int* __restrict__ pred, const float* __restrict__ pval,
    const int* __restrict__ lengths, float* __restrict__ w,
    int* __restrict__ bpos, int* __restrict__ nseg,
    float* __restrict__ out_nl) {
  const int b    = blockIdx.x;
  const int tid  = threadIdx.x;
  const int lane = tid & 63;
  const int wid  = tid >> 6;  // 16 waves
  const int len  = lengths[b];

  __shared__ float segsum[T];  // 8 KB
  __shared__ int wsum[16];
  __shared__ int wscan[16];
  for (int i = tid; i < T; i += 1024) segsum[i] = 0.f;

  const int t0 = tid * 2;
  const int2   pt = *reinterpret_cast<const int2*>(pred + b * T + t0);
  const float2 pv = *reinterpret_cast<const float2*>(pval + b * T + t0);
  const int prev = (t0 > 0) ? pred[b * T + t0 - 1] : -1;

  const bool nbb0 = (t0 < len)     && (pt.x != prev) && (pt.x != BLANK_ID);
  const bool nbb1 = (t0 + 1 < len) && (pt.y != pt.x) && (pt.y != BLANK_ID);
  const bool fis0 = (t0 < len)     && (pt.x != BLANK_ID);
  const bool fis1 = (t0 + 1 < len) && (pt.y != BLANK_ID);
  const int c = (int)nbb0 + (int)nbb1;

  // wave64 inclusive scan
  int x = c;
#pragma unroll
  for (int off = 1; off < 64; off <<= 1) {
    const int v = __shfl_up(x, off);
    if (lane >= off) x += v;
  }
  if (lane == 63) wsum[wid] = x;
  __syncthreads();
  if (tid < 16) {
    int v = wsum[tid];
#pragma unroll
    for (int off = 1; off < 16; off <<= 1) {
      const int u = __shfl_up(v, off);
      if (tid >= off) v += u;
    }
    wscan[tid] = v;
  }
  __syncthreads();
  const int excl  = ((wid > 0) ? wscan[wid - 1] : 0) + x - c;
  const int total = wscan[15];

  int run = excl;
  if (nbb0) { bpos[b * (T + 1) + run] = t0; ++run; }
  const int seg0 = run - 1;
  if (fis0 && seg0 >= 0) atomicAdd(&segsum[seg0], pv.x);
  if (nbb1) { bpos[b * (T + 1) + run] = t0 + 1; ++run; }
  const int seg1 = run - 1;
  if (fis1 && seg1 >= 0) atomicAdd(&segsum[seg1], pv.y);
  __syncthreads();

  const float w0 = (fis0 && seg0 >= 0) ? pv.x / (segsum[seg0] + EPS) : 0.f;
  const float w1 = (fis1 && seg1 >= 0) ? pv.y / (segsum[seg1] + EPS) : 0.f;
  *reinterpret_cast<float2*>(w + b * T + t0) = make_float2(w0, w1);

  if (tid == 0) {
    nseg[b] = total;
    bpos[b * (T + 1) + total] = len;  // sentinel end of last segment
    if (out_nl) out_nl[b] = (float)(total > 0 ? total : 1);
  }
}

// ---------------------------------------------------------------------------
// Phase 3: one WAVE per output row (b,s); 4 waves/block -> 4x fewer blocks,
// no block syncs, 4 independent float4 loads in flight per lane. Rows
// s >= n_seg write zeros (d_out is poisoned). Nontemporal stores: output is
// written once, never re-read -> keep L2 for hidden_states.
// ---------------------------------------------------------------------------
__global__ __launch_bounds__(256) void k_compress(
    const float* __restrict__ hidden, const float* __restrict__ w,
    const int* __restrict__ bpos, const int* __restrict__ nseg,
    const float* __restrict__ p0, const int* __restrict__ lengths,
    float* __restrict__ out) {
  const int wid  = threadIdx.x >> 6;
  const int lane = threadIdx.x & 63;
  const int s = blockIdx.x * 4 + wid;
  const int b = blockIdx.y;
  const int n = nseg[b];

  float4 acc[4];
#pragma unroll
  for (int k = 0; k < 4; ++k) acc[k] = make_float4(0.f, 0.f, 0.f, 0.f);

  if (s < n) {
    const int st = bpos[b * (T + 1) + s];
    const int en = bpos[b * (T + 1) + s + 1];
    for (int t = st; t < en; ++t) {
      const float wt = w[b * T + t];  // uniform across wave -> one request
      if (wt != 0.f) {
        const float* hp = hidden + ((size_t)(b * T + t)) * D + lane * 4;
#pragma unroll
        for (int k = 0; k < 4; ++k) {
          const float4 h = *reinterpret_cast<const float4*>(hp + k * 256);
          acc[k].x += wt * h.x; acc[k].y += wt * h.y;
          acc[k].z += wt * h.z; acc[k].w += wt * h.w;
        }
      }
    }
  } else if (s == 0 && n == 0 && lengths[b] >= 1) {
    const float pv = p0[b];
    const float wt = pv / (pv + EPS);
    const float* hp = hidden + (size_t)b * T * D + lane * 4;
#pragma unroll
    for (int k = 0; k < 4; ++k) {
      const float4 h = *reinterpret_cast<const float4*>(hp + k * 256);
      acc[k] = make_float4(wt * h.x, wt * h.y, wt * h.z, wt * h.w);
    }
  }

  float* op = out + ((size_t)(b * T + s)) * D + lane * 4;
#pragma unroll
  for (int k = 0; k < 4; ++k) {
    __builtin_nontemporal_store(acc[k].x, op + k * 256 + 0);
    __builtin_nontemporal_store(acc[k].y, op + k * 256 + 1);
    __builtin_nontemporal_store(acc[k].z, op + k * 256 + 2);
    __builtin_nontemporal_store(acc[k].w, op + k * 256 + 3);
  }
}

// ---------------------------------------------------------------------------
extern "C" void kernel_launch(void* const* d_in, const int* in_sizes, int n_in,
                              void* d_out, int out_size, void* d_ws,
                              size_t ws_size, hipStream_t stream) {
  const float* hidden  = (const float*)d_in[0];
  const float* logits  = (const float*)d_in[1];
  const int*   lengths = (const int*)d_in[2];
  float* out = (float*)d_out;

  char* ws = (char*)d_ws;
  int*   pred = (int*)ws;   ws += (size_t)B * T * sizeof(int);
  float* pval = (float*)ws; ws += (size_t)B * T * sizeof(float);
  float* wgt  = (float*)ws; ws += (size_t)B * T * sizeof(float);
  int*   bpos = (int*)ws;   ws += (size_t)B * (T + 1) * sizeof(int);
  int*   nseg = (int*)ws;   ws += (size_t)B * sizeof(int);
  float* p0   = (float*)ws; ws += (size_t)B * sizeof(float);

  // tuple output: [compressed (B*T*D floats) | new_lengths (B, as float)]
  float* out_nl =
      (out_size >= B * T * D + B) ? out + (size_t)B * T * D : nullptr;

  k_softmax_stats<<<(B * T) / 4, 256, 0, stream>>>(logits, pred, pval, p0);
  k_segment<<<B, 1024, 0, stream>>>(pred, pval, lengths, wgt, bpos, nseg,
                                    out_nl);
  dim3 g3(T / 4, B);
  k_compress<<<g3, 256, 0, stream>>>(hidden, wgt, bpos, nseg, p0, lengths,
                                     out);
}

// Round 5
// 179.489 us; speedup vs baseline: 1.0147x; 1.0147x over previous
//
#include <hip/hip_runtime.h>

#define BLANK_ID 0
#define EPS 1e-10f

constexpr int B = 8, T = 2048, D = 1024, V = 1024;

// ---------------------------------------------------------------------------
// Phase 1: per-(b,t) softmax stats. One wave64 per row of V=1024 logits.
// Each lane holds 16 elements (4x float4, coalesced). Outputs: pred=argmax,
// pval=1/sumexp (== prob of argmax), p0[b]=blank prob at t=0 (fallback only).
// ---------------------------------------------------------------------------
__global__ __launch_bounds__(256) void k_softmax_stats(
    const float* __restrict__ logits, int* __restrict__ pred,
    float* __restrict__ pval, float* __restrict__ p0) {
  const int wave = threadIdx.x >> 6;
  const int lane = threadIdx.x & 63;
  const int row  = blockIdx.x * 4 + wave;  // [0, B*T)
  const float* rp = logits + (size_t)row * V;

  float4 x[4];
#pragma unroll
  for (int j = 0; j < 4; ++j)
    x[j] = *reinterpret_cast<const float4*>(rp + j * 256 + lane * 4);

  // local max + argmax (first occurrence on ties, matching jnp.argmax)
  float m = x[0].x;
  int idx = lane * 4;
#pragma unroll
  for (int j = 0; j < 4; ++j) {
    const float v[4] = {x[j].x, x[j].y, x[j].z, x[j].w};
#pragma unroll
    for (int k = 0; k < 4; ++k) {
      const int vi = j * 256 + lane * 4 + k;
      if (v[k] > m || (v[k] == m && vi < idx)) { m = v[k]; idx = vi; }
    }
  }
#pragma unroll
  for (int off = 32; off > 0; off >>= 1) {
    const float om = __shfl_xor(m, off);
    const int   oi = __shfl_xor(idx, off);
    if (om > m || (om == m && oi < idx)) { m = om; idx = oi; }
  }

  float s = 0.f;
#pragma unroll
  for (int j = 0; j < 4; ++j)
    s += __expf(x[j].x - m) + __expf(x[j].y - m) +
         __expf(x[j].z - m) + __expf(x[j].w - m);
#pragma unroll
  for (int off = 32; off > 0; off >>= 1) s += __shfl_xor(s, off);

  if (lane == 0) {
    pred[row] = idx;
    pval[row] = 1.0f / s;
    if ((row & (T - 1)) == 0) p0[row / T] = __expf(x[0].x - m) / s;
  }
}

// ---------------------------------------------------------------------------
// Phase 2: per-batch segment scan. 1024 threads x 2 t's. Wave-level shfl_up
// scan (3 barriers). seg_idx is monotone in t so segment s == t-range
// [bpos[s], bpos[s+1]). w[t]=p/(segsum+EPS) for contributing frames else 0.
// ---------------------------------------------------------------------------
__global__ __launch_bounds__(1024) void k_segment(
    const int* __restrict__ pred, const float* __restrict__ pval,
    const int* __restrict__ lengths, float* __restrict__ w,
    int* __restrict__ bpos, int* __restrict__ nseg,
    float* __restrict__ out_nl) {
  const int b    = blockIdx.x;
  const int tid  = threadIdx.x;
  const int lane = tid & 63;
  const int wid  = tid >> 6;  // 16 waves
  const int len  = lengths[b];

  __shared__ float segsum[T];  // 8 KB
  __shared__ int wsum[16];
  __shared__ int wscan[16];
  for (int i = tid; i < T; i += 1024) segsum[i] = 0.f;

  const int t0 = tid * 2;
  const int2   pt = *reinterpret_cast<const int2*>(pred + b * T + t0);
  const float2 pv = *reinterpret_cast<const float2*>(pval + b * T + t0);
  const int prev = (t0 > 0) ? pred[b * T + t0 - 1] : -1;

  const bool nbb0 = (t0 < len)     && (pt.x != prev) && (pt.x != BLANK_ID);
  const bool nbb1 = (t0 + 1 < len) && (pt.y != pt.x) && (pt.y != BLANK_ID);
  const bool fis0 = (t0 < len)     && (pt.x != BLANK_ID);
  const bool fis1 = (t0 + 1 < len) && (pt.y != BLANK_ID);
  const int c = (int)nbb0 + (int)nbb1;

  // wave64 inclusive scan
  int x = c;
#pragma unroll
  for (int off = 1; off < 64; off <<= 1) {
    const int v = __shfl_up(x, off);
    if (lane >= off) x += v;
  }
  if (lane == 63) wsum[wid] = x;
  __syncthreads();
  if (tid < 16) {
    int v = wsum[tid];
#pragma unroll
    for (int off = 1; off < 16; off <<= 1) {
      const int u = __shfl_up(v, off);
      if (tid >= off) v += u;
    }
    wscan[tid] = v;
  }
  __syncthreads();
  const int excl  = ((wid > 0) ? wscan[wid - 1] : 0) + x - c;
  const int total = wscan[15];

  int run = excl;
  if (nbb0) { bpos[b * (T + 1) + run] = t0; ++run; }
  const int seg0 = run - 1;
  if (fis0 && seg0 >= 0) atomicAdd(&segsum[seg0], pv.x);
  if (nbb1) { bpos[b * (T + 1) + run] = t0 + 1; ++run; }
  const int seg1 = run - 1;
  if (fis1 && seg1 >= 0) atomicAdd(&segsum[seg1], pv.y);
  __syncthreads();

  const float w0 = (fis0 && seg0 >= 0) ? pv.x / (segsum[seg0] + EPS) : 0.f;
  const float w1 = (fis1 && seg1 >= 0) ? pv.y / (segsum[seg1] + EPS) : 0.f;
  *reinterpret_cast<float2*>(w + b * T + t0) = make_float2(w0, w1);

  if (tid == 0) {
    nseg[b] = total;
    bpos[b * (T + 1) + total] = len;  // sentinel end of last segment
    if (out_nl) out_nl[b] = (float)(total > 0 ? total : 1);
  }
}

// ---------------------------------------------------------------------------
// Phase 3: one WAVE per output row (b,s). 4-wide unrolled frame loop with
// UNCONDITIONAL hidden loads (w=0 discards blanks arithmetically): all
// 4 w-loads + 16 float4 h-loads issue back-to-back -> chain depth 2 memory
// round-trips instead of ~4-5 (was 2.3 TB/s latency-bound). Tail frames
// clamp to t=st with weight 0. Rows s >= n_seg write zeros (d_out poisoned).
// NT stores: output written once, never re-read.
// ---------------------------------------------------------------------------
__global__ __launch_bounds__(256) void k_compress(
    const float* __restrict__ hidden, const float* __restrict__ w,
    const int* __restrict__ bpos, const int* __restrict__ nseg,
    const float* __restrict__ p0, const int* __restrict__ lengths,
    float* __restrict__ out) {
  const int wid  = threadIdx.x >> 6;
  const int lane = threadIdx.x & 63;
  const int s = blockIdx.x * 4 + wid;
  const int b = blockIdx.y;
  const int n = nseg[b];

  float4 acc[4];
#pragma unroll
  for (int k = 0; k < 4; ++k) acc[k] = make_float4(0.f, 0.f, 0.f, 0.f);

  if (s < n) {
    const int st = bpos[b * (T + 1) + s];
    const int en = bpos[b * (T + 1) + s + 1];
    for (int t = st; t < en; t += 4) {
      float wv[4];
      int   tt[4];
#pragma unroll
      for (int j = 0; j < 4; ++j) {
        const bool ok = (t + j) < en;
        tt[j] = ok ? (t + j) : st;
        wv[j] = ok ? w[b * T + t + j] : 0.f;
      }
      float4 h[4][4];
#pragma unroll
      for (int j = 0; j < 4; ++j) {
        const float* hp = hidden + ((size_t)(b * T + tt[j])) * D + lane * 4;
#pragma unroll
        for (int k = 0; k < 4; ++k)
          h[j][k] = *reinterpret_cast<const float4*>(hp + k * 256);
      }
#pragma unroll
      for (int j = 0; j < 4; ++j) {
#pragma unroll
        for (int k = 0; k < 4; ++k) {
          acc[k].x += wv[j] * h[j][k].x;
          acc[k].y += wv[j] * h[j][k].y;
          acc[k].z += wv[j] * h[j][k].z;
          acc[k].w += wv[j] * h[j][k].w;
        }
      }
    }
  } else if (s == 0 && n == 0 && lengths[b] >= 1) {
    const float pv = p0[b];
    const float wt = pv / (pv + EPS);
    const float* hp = hidden + (size_t)b * T * D + lane * 4;
#pragma unroll
    for (int k = 0; k < 4; ++k) {
      const float4 h = *reinterpret_cast<const float4*>(hp + k * 256);
      acc[k] = make_float4(wt * h.x, wt * h.y, wt * h.z, wt * h.w);
    }
  }

  float* op = out + ((size_t)(b * T + s)) * D + lane * 4;
#pragma unroll
  for (int k = 0; k < 4; ++k) {
    __builtin_nontemporal_store(acc[k].x, op + k * 256 + 0);
    __builtin_nontemporal_store(acc[k].y, op + k * 256 + 1);
    __builtin_nontemporal_store(acc[k].z, op + k * 256 + 2);
    __builtin_nontemporal_store(acc[k].w, op + k * 256 + 3);
  }
}

// ---------------------------------------------------------------------------
extern "C" void kernel_launch(void* const* d_in, const int* in_sizes, int n_in,
                              void* d_out, int out_size, void* d_ws,
                              size_t ws_size, hipStream_t stream) {
  const float* hidden  = (const float*)d_in[0];
  const float* logits  = (const float*)d_in[1];
  const int*   lengths = (const int*)d_in[2];
  float* out = (float*)d_out;

  char* ws = (char*)d_ws;
  int*   pred = (int*)ws;   ws += (size_t)B * T * sizeof(int);
  float* pval = (float*)ws; ws += (size_t)B * T * sizeof(float);
  float* wgt  = (float*)ws; ws += (size_t)B * T * sizeof(float);
  int*   bpos = (int*)ws;   ws += (size_t)B * (T + 1) * sizeof(int);
  int*   nseg = (int*)ws;   ws += (size_t)B * sizeof(int);
  float* p0   = (float*)ws; ws += (size_t)B * sizeof(float);

  // tuple output: [compressed (B*T*D floats) | new_lengths (B, as float)]
  float* out_nl =
      (out_size >= B * T * D + B) ? out + (size_t)B * T * D : nullptr;

  k_softmax_stats<<<(B * T) / 4, 256, 0, stream>>>(logits, pred, pval, p0);
  k_segment<<<B, 1024, 0, stream>>>(pred, pval, lengths, wgt, bpos, nseg,
                                    out_nl);
  dim3 g3(T / 4, B);
  k_compress<<<g3, 256, 0, stream>>>(hidden, wgt, bpos, nseg, p0, lengths,
                                     out);
}